// Round 1
// baseline (112.559 us; speedup 1.0000x reference)
//
#include <hip/hip_runtime.h>
#include <hip/hip_bf16.h>
#include <cstdint>

// NT-Xent contrastive loss, B=4096, D=128, T=0.1.
// loss = sum_i [ log(sum_{j!=i} exp(s_ij)) - s_{i,partner(i)} ] * (B/2)
// s_ij = 10 * cos(n_i, n_j).  We store n * sqrt(10*log2e) in bf16 so the
// MFMA accumulator is directly the exp2 argument (s * log2e).
//
// This version exploits symmetry: s_ij == s_ji bit-exactly (same MFMA
// product tree), so each strictly-above-diagonal 128x256 tile feeds both
// rowsum[i] (row reduce) and rowsum[j] (col reduce via shfl + LDS + atomic).
// Tile set: for col-block cb (256 cols), keep row-blocks rb < 2*(cb+1):
// rb < 2*cb are "above" (double-use), rb in {2cb, 2cb+1} are the diagonal
// band (computed fully, row-sums only). Work = 0.516x of the full matrix.

typedef __bf16 bf16x8 __attribute__((ext_vector_type(8)));
typedef __bf16 bf16x2 __attribute__((ext_vector_type(2)));
typedef float  f32x4  __attribute__((ext_vector_type(4)));

#define NROWS 8192
#define DIM   128
#define ALPHA 3.7982827f            /* sqrt(10 * log2(e)) */
#define LN2   0.6931471805599453f

// ---- async global->LDS, 16B per lane, wave-uniform LDS base ----
__device__ __forceinline__ void load_lds16(const void* g, void* l) {
    __builtin_amdgcn_global_load_lds(
        (const __attribute__((address_space(1))) unsigned int*)(uintptr_t)g,
        (__attribute__((address_space(3))) unsigned int*)(uintptr_t)l,
        16, 0, 0);
}

// K-chunk xor swizzle: element k of row r stored at chunk c' = (c&8)|((c^r)&7),
// c = k>>3.  Keeps ds_read_b128 fragment reads at free 2-way bank conflicts,
// while remaining a contiguous-per-row layout (global_load_lds compatible).

// ---------------- Kernel A: normalize + scale + swizzle + zero ws ----------
__global__ __launch_bounds__(256) void norm_kernel(
    const float* __restrict__ out1, const float* __restrict__ out2,
    __bf16* __restrict__ nb, float* __restrict__ rowsum, float* __restrict__ dout)
{
    const int t = threadIdx.x, lane = t & 63, wid = t >> 6;
    const int row = blockIdx.x * 4 + wid;
    const float* src = (row < 4096) ? (out1 + (size_t)row * DIM)
                                    : (out2 + (size_t)(row - 4096) * DIM);
    float2 v = ((const float2*)src)[lane];
    float ss = v.x * v.x + v.y * v.y;
    #pragma unroll
    for (int off = 1; off < 64; off <<= 1) ss += __shfl_xor(ss, off);
    const float s = rsqrtf(ss) * ALPHA;

    const int c  = lane >> 2;                      // chunk of element 2*lane
    const int cs = (c & 8) | ((c ^ row) & 7);
    const int idx = row * DIM + cs * 8 + ((2 * lane) & 7);
    bf16x2 w;
    w.x = (__bf16)(v.x * s);
    w.y = (__bf16)(v.y * s);
    *(bf16x2*)(nb + idx) = w;

    if (blockIdx.x < 32) rowsum[blockIdx.x * 256 + t] = 0.0f;
    if (blockIdx.x == 0 && t == 0) dout[0] = 0.0f;
}

// ---------------- Kernel B: triangular Gram + exp + row/col sums ----------
// 1056 blocks; block b -> (cb, rb) with cb*(cb+1) <= b < (cb+1)*(cb+2),
// rb = b - cb*(cb+1).  Tile = rows [rb*128,+128) x cols [cb*256,+256).
// 4 waves in 2x2; each wave owns a 64x64 output tile per 128-col step (ct).
// A-strip fragments register-resident; B staged double-buffered via
// global_load_lds so the second stage drains after ct0's compute.
__global__ __launch_bounds__(256, 2) void simloss_main(
    const __bf16* __restrict__ nb, float* __restrict__ rowsum)
{
    __shared__ __bf16 Bsm[2][128 * DIM];          // 2 x 32 KB (double buffer)
    __shared__ float colpart[256];                // per-tile column partials

    const int t = threadIdx.x, lane = t & 63, wid = t >> 6;
    const int quad = lane >> 4, l15 = lane & 15;

    // decode triangular block index
    const int b = (int)blockIdx.x;
    int cb = (int)(0.5f * (sqrtf(4.0f * (float)b + 1.0f) - 1.0f));
    if (cb < 0) cb = 0;
    while (cb > 0 && cb * (cb + 1) > b) --cb;
    while ((cb + 1) * (cb + 2) <= b) ++cb;
    const int rb = b - cb * (cb + 1);
    const int above = (rb < 2 * cb);              // strictly above diagonal band

    const int rowbase = rb * 128 + (wid & 1) * 64;   // global row of wave tile
    const int ncol0   = (wid >> 1) * 64;             // col offset inside ct tile
    const int colblk  = cb * 256;                    // first col of tile

    // swizzled chunk byte/element offsets per k-step
    int cso[4];
    #pragma unroll
    for (int k = 0; k < 4; ++k) {
        int c = k * 4 + quad;
        cso[k] = ((c & 8) | ((c ^ lane) & 7)) * 8;   // lane&7 == row&7 here
    }

    // stage ct=0 (cols colblk..+128 => 128 contiguous rows of nb) into Bsm[0]
    {
        const char* gB  = (const char*)(nb + (size_t)colblk * DIM);
        char*       lB  = (char*)(&Bsm[0][0]) + wid * 1024;
        const char* gBw = gB + wid * 1024 + lane * 16;
        #pragma unroll
        for (int i = 0; i < 8; ++i) load_lds16(gBw + i * 4096, lB + i * 4096);
    }

    colpart[t] = 0.0f;

    // A fragments from global (L2-hot), 16 x 16B per lane
    bf16x8 afrag[4][4];
    #pragma unroll
    for (int mt = 0; mt < 4; ++mt) {
        const __bf16* ar = nb + (size_t)(rowbase + mt * 16 + l15) * DIM;
        #pragma unroll
        for (int k = 0; k < 4; ++k) afrag[mt][k] = *(const bf16x8*)(ar + cso[k]);
    }

    float rowpart[4][4] = {};

    __syncthreads();   // stage0 + afrag drained; colpart zero visible

    // issue stage ct=1 now: its vmcnt drain lands at the barrier AFTER ct0
    {
        const char* gB  = (const char*)(nb + (size_t)(colblk + 128) * DIM);
        char*       lB  = (char*)(&Bsm[1][0]) + wid * 1024;
        const char* gBw = gB + wid * 1024 + lane * 16;
        #pragma unroll
        for (int i = 0; i < 8; ++i) load_lds16(gBw + i * 4096, lB + i * 4096);
    }

    #pragma unroll
    for (int ct = 0; ct < 2; ++ct) {
        const __bf16* Bs = &Bsm[ct][0];
        f32x4 acc[4][4] = {};
        #pragma unroll
        for (int k = 0; k < 4; ++k) {
            bf16x8 bfr[4];
            #pragma unroll
            for (int nt = 0; nt < 4; ++nt)
                bfr[nt] = *(const bf16x8*)(Bs + (ncol0 + nt * 16 + l15) * DIM + cso[k]);
            #pragma unroll
            for (int mt = 0; mt < 4; ++mt)
                #pragma unroll
                for (int nt = 0; nt < 4; ++nt)
                    acc[mt][nt] = __builtin_amdgcn_mfma_f32_16x16x32_bf16(
                        afrag[mt][k], bfr[nt], acc[mt][nt], 0, 0, 0);
        }

        // epilogue: acc is already s*log2e -> single v_exp_f32 each.
        // rowpart: sum over cols (nt, l15);  csum: sum over rows (mt, r, quad).
        float csum[4] = {};
        #pragma unroll
        for (int mt = 0; mt < 4; ++mt)
            #pragma unroll
            for (int nt = 0; nt < 4; ++nt) {
                float cs = 0.0f;
                #pragma unroll
                for (int r = 0; r < 4; ++r) {
                    float e = __builtin_amdgcn_exp2f(acc[mt][nt][r]);
                    rowpart[mt][r] += e;
                    cs += e;
                }
                csum[nt] += cs;
            }

        if (above) {
            // finish col reduce across quads; 16 lanes own 16 distinct cols
            #pragma unroll
            for (int nt = 0; nt < 4; ++nt) {
                float v = csum[nt];
                v += __shfl_xor(v, 16);
                v += __shfl_xor(v, 32);
                if (quad == 0)
                    atomicAdd(&colpart[ct * 128 + ncol0 + nt * 16 + l15], v);
            }
        }
        if (ct == 0) __syncthreads();   // Bsm[1] staged (vmcnt drained here)
    }

    __syncthreads();   // all colpart LDS-atomics complete

    // row sums: reduce the 16 lanes sharing a quad (cols), one atomic per row
    #pragma unroll
    for (int mt = 0; mt < 4; ++mt)
        #pragma unroll
        for (int r = 0; r < 4; ++r) {
            float v = rowpart[mt][r];
            v += __shfl_xor(v, 1);
            v += __shfl_xor(v, 2);
            v += __shfl_xor(v, 4);
            v += __shfl_xor(v, 8);
            if (l15 == 0)
                atomicAdd(&rowsum[rowbase + mt * 16 + quad * 4 + r], v);
        }

    // symmetric contribution: this tile's exp(s_ij) is also row j's term
    if (above)
        atomicAdd(&rowsum[colblk + t], colpart[t]);
}

// ---------------- Kernel C: subtract diag, logs, positive pairs, reduce ----
__global__ __launch_bounds__(256) void finalize_kernel(
    const __bf16* __restrict__ nb, const float* __restrict__ rowsum,
    float* __restrict__ dout)
{
    const int t = threadIdx.x, lane = t & 63, wid = t >> 6;
    const int w = blockIdx.x * 4 + wid;            // 2048 waves, 4 rows each
    float wacc = 0.0f;
    #pragma unroll
    for (int rr = 0; rr < 4; ++rr) {
        const int i = w * 4 + rr;
        const int p = i ^ 4096;                    // partner row (B=4096, pow2)
        // rows i and p share (row&7) so the k-swizzle cancels in the dot
        bf16x2 av = *(const bf16x2*)(nb + (size_t)i * DIM + 2 * lane);
        bf16x2 bv = *(const bf16x2*)(nb + (size_t)p * DIM + 2 * lane);
        float ax = (float)av.x, ay = (float)av.y;
        float bx = (float)bv.x, by = (float)bv.y;
        float self = ax * ax + ay * ay;            // -> 10*log2e exactly as MFMA saw it
        float pos  = ax * bx + ay * by;            // s_pos * log2e
        #pragma unroll
        for (int off = 1; off < 64; off <<= 1) {
            self += __shfl_xor(self, off);
            pos  += __shfl_xor(pos, off);
        }
        if (lane == 0) {
            float se = rowsum[i] - __builtin_amdgcn_exp2f(self);  // drop diagonal
            wacc += logf(se) - pos * LN2;          // lse_nat - s_pos_nat
        }
    }
    if (lane == 0) atomicAdd(dout, wacc * 2048.0f); // * B/2
}

extern "C" void kernel_launch(void* const* d_in, const int* in_sizes, int n_in,
                              void* d_out, int out_size, void* d_ws, size_t ws_size,
                              hipStream_t stream)
{
    const float* out1 = (const float*)d_in[0];
    const float* out2 = (const float*)d_in[1];
    __bf16* nb     = (__bf16*)d_ws;                               // 2 MB
    float*  rowsum = (float*)((char*)d_ws + (size_t)NROWS * DIM * 2); // 32 KB
    float*  dout   = (float*)d_out;

    hipLaunchKernelGGL(norm_kernel, dim3(2048), dim3(256), 0, stream,
                       out1, out2, nb, rowsum, dout);
    hipLaunchKernelGGL(simloss_main, dim3(1056), dim3(256), 0, stream,
                       (const __bf16*)nb, rowsum);
    hipLaunchKernelGGL(finalize_kernel, dim3(512), dim3(256), 0, stream,
                       (const __bf16*)nb, rowsum, dout);
}

// Round 2
// 110.065 us; speedup vs baseline: 1.0227x; 1.0227x over previous
//
#include <hip/hip_runtime.h>
#include <hip/hip_bf16.h>
#include <cstdint>

// NT-Xent contrastive loss, B=4096, D=128, T=0.1.
// loss = sum_i [ log(sum_{j!=i} exp(s_ij)) - s_{i,partner(i)} ] * (B/2)
// s_ij = 10 * cos(n_i, n_j).  We store n * sqrt(10*log2e) in bf16 so the
// MFMA accumulator is directly the exp2 argument (s * log2e).
//
// Symmetric Gram: s_ij == s_ji bit-exactly (same MFMA product tree).
// Work tiles are 128x128 blocks of the upper triangle (rb <= cbb), 2080
// tasks.  Off-diagonal tasks credit both rowsum[i] (row reduce) and
// rowsum[j] (col reduce, LDS colpart -> global atomic).  Diagonal tasks
// (rb==cbb) are computed fully, row sums only.
// Load balance: pair row m with row 63-m -> 65 tasks/pair, 32 pairs,
// 16 blocks/pair taking 4-5 contiguous tasks -> exactly 512 uniform
// blocks, all co-resident at 2/CU, <=1 afrag reload per block.
// Staging is pipelined: next task's B-block global_load_lds issued before
// the current k-loop; single barrier per task drains it (T3-minimum).

typedef __bf16 bf16x8 __attribute__((ext_vector_type(8)));
typedef __bf16 bf16x2 __attribute__((ext_vector_type(2)));
typedef float  f32x4  __attribute__((ext_vector_type(4)));

#define NROWS 8192
#define DIM   128
#define ALPHA 3.7982827f            /* sqrt(10 * log2(e)) */
#define LN2   0.6931471805599453f

// ---- async global->LDS, 16B per lane, wave-uniform LDS base ----
__device__ __forceinline__ void load_lds16(const void* g, void* l) {
    __builtin_amdgcn_global_load_lds(
        (const __attribute__((address_space(1))) unsigned int*)(uintptr_t)g,
        (__attribute__((address_space(3))) unsigned int*)(uintptr_t)l,
        16, 0, 0);
}

// K-chunk xor swizzle: element k of row r stored at chunk c' = (c&8)|((c^r)&7),
// c = k>>3.  Keeps ds_read_b128 fragment reads at free 2-way bank conflicts,
// while remaining a contiguous-per-row layout (global_load_lds compatible).

// ---------------- Kernel A: normalize + scale + swizzle + zero ws ----------
__global__ __launch_bounds__(256) void norm_kernel(
    const float* __restrict__ out1, const float* __restrict__ out2,
    __bf16* __restrict__ nb, float* __restrict__ rowsum, float* __restrict__ dout)
{
    const int t = threadIdx.x, lane = t & 63, wid = t >> 6;
    const int row = blockIdx.x * 4 + wid;
    const float* src = (row < 4096) ? (out1 + (size_t)row * DIM)
                                    : (out2 + (size_t)(row - 4096) * DIM);
    float2 v = ((const float2*)src)[lane];
    float ss = v.x * v.x + v.y * v.y;
    #pragma unroll
    for (int off = 1; off < 64; off <<= 1) ss += __shfl_xor(ss, off);
    const float s = rsqrtf(ss) * ALPHA;

    const int c  = lane >> 2;                      // chunk of element 2*lane
    const int cs = (c & 8) | ((c ^ row) & 7);
    const int idx = row * DIM + cs * 8 + ((2 * lane) & 7);
    bf16x2 w;
    w.x = (__bf16)(v.x * s);
    w.y = (__bf16)(v.y * s);
    *(bf16x2*)(nb + idx) = w;

    if (blockIdx.x < 32) rowsum[blockIdx.x * 256 + t] = 0.0f;
    if (blockIdx.x == 0 && t == 0) dout[0] = 0.0f;
}

// ---------------- Kernel B: triangular Gram + exp + row/col sums ----------
__global__ __launch_bounds__(256, 2) void simloss_main(
    const __bf16* __restrict__ nb, float* __restrict__ rowsum)
{
    __shared__ __bf16 Bsm[2][128 * DIM];          // 2 x 32 KB double buffer
    __shared__ float colpart[2][128];             // parity-alternating col sums

    const int t = threadIdx.x, lane = t & 63, wid = t >> 6;
    const int quad = lane >> 4, l15 = lane & 15;
    const int ncol0 = (wid >> 1) * 64;            // col offset inside task

    // ---- task range: pair m = {row m, row 63-m}, 65 tasks, 16 chunks ----
    const int m = (int)blockIdx.x >> 4;           // pair 0..31
    const int ch = (int)blockIdx.x & 15;
    const int s = (ch * 65) >> 4;                 // local task start
    const int e = ((ch + 1) * 65) >> 4;           // local task end (4-5 tasks)
    const int row0len = 64 - m;

    int rb, cbb;
    if (s < row0len) { rb = m;      cbb = m + s; }
    else             { rb = 63 - m; cbb = (63 - m) + (s - row0len); }
    int rowbase = rb * 128 + (wid & 1) * 64;

    // swizzled chunk byte/element offsets per k-step
    int cso[4];
    #pragma unroll
    for (int k = 0; k < 4; ++k) {
        int c = k * 4 + quad;
        cso[k] = ((c & 8) | ((c ^ lane) & 7)) * 8;   // lane&7 == row&7 here
    }

    // stage B-block cb (128 rows of nb = 32 KB) into Bsm[bi]
    #define STAGE(bi, cb) do {                                               \
        const char* gBw_ = (const char*)nb + (size_t)(cb) * 32768            \
                           + wid * 1024 + lane * 16;                         \
        char* lB_ = (char*)(&Bsm[bi][0]) + wid * 1024;                       \
        _Pragma("unroll")                                                    \
        for (int i_ = 0; i_ < 8; ++i_)                                       \
            load_lds16(gBw_ + i_ * 4096, lB_ + i_ * 4096);                   \
    } while (0)

    bf16x8 afrag[4][4];
    #define LOAD_AFRAG() do {                                                \
        _Pragma("unroll")                                                    \
        for (int mt_ = 0; mt_ < 4; ++mt_) {                                  \
            const __bf16* ar_ = nb + (size_t)(rowbase + mt_ * 16 + l15) * DIM; \
            _Pragma("unroll")                                                \
            for (int k_ = 0; k_ < 4; ++k_)                                   \
                afrag[mt_][k_] = *(const bf16x8*)(ar_ + cso[k_]);            \
        }                                                                    \
    } while (0)

    float rowpart[4][4] = {};
    #define FLUSH_ROWS() do {                                                \
        _Pragma("unroll")                                                    \
        for (int mt_ = 0; mt_ < 4; ++mt_)                                    \
            _Pragma("unroll")                                                \
            for (int r_ = 0; r_ < 4; ++r_) {                                 \
                float v_ = rowpart[mt_][r_];                                 \
                v_ += __shfl_xor(v_, 1);                                     \
                v_ += __shfl_xor(v_, 2);                                     \
                v_ += __shfl_xor(v_, 4);                                     \
                v_ += __shfl_xor(v_, 8);                                     \
                if (l15 == 0)                                                \
                    atomicAdd(&rowsum[rowbase + mt_ * 16 + quad * 4 + r_], v_); \
            }                                                                \
    } while (0)

    // prologue: stage first task, zero colpart, load afrag
    STAGE(0, cbb);
    ((float*)colpart)[t] = 0.0f;      // 256 entries, t covers all
    LOAD_AFRAG();
    __syncthreads();                   // stage0 + afrag drained, zeros visible

    int buf = 0;
    for (int task = s; task < e; ++task) {
        const bool isLast = (task == e - 1);
        const bool wrap = (cbb == 63) && (rb == m);   // next task is 2nd row
        const int ncbb = wrap ? (63 - m) : (cbb + 1);
        if (!isLast) STAGE(buf ^ 1, ncbb);            // pipelined prefetch

        // ---- k-loop: 64 MFMA from Bsm[buf] ----
        const __bf16* Bs = &Bsm[buf][0];
        f32x4 acc[4][4] = {};
        #pragma unroll
        for (int k = 0; k < 4; ++k) {
            bf16x8 bfr[4];
            #pragma unroll
            for (int nt = 0; nt < 4; ++nt)
                bfr[nt] = *(const bf16x8*)(Bs + (ncol0 + nt * 16 + l15) * DIM + cso[k]);
            #pragma unroll
            for (int mt = 0; mt < 4; ++mt)
                #pragma unroll
                for (int nt = 0; nt < 4; ++nt)
                    acc[mt][nt] = __builtin_amdgcn_mfma_f32_16x16x32_bf16(
                        afrag[mt][k], bfr[nt], acc[mt][nt], 0, 0, 0);
        }

        // ---- epilogue: exp2; row partials always, col partials if off-diag
        const bool diag = (rb == cbb);
        float csum[4] = {};
        #pragma unroll
        for (int mt = 0; mt < 4; ++mt)
            #pragma unroll
            for (int nt = 0; nt < 4; ++nt) {
                float cs = 0.0f;
                #pragma unroll
                for (int r = 0; r < 4; ++r) {
                    float e2 = __builtin_amdgcn_exp2f(acc[mt][nt][r]);
                    rowpart[mt][r] += e2;
                    cs += e2;
                }
                csum[nt] += cs;
            }
        if (!diag) {
            #pragma unroll
            for (int nt = 0; nt < 4; ++nt) {
                float v = csum[nt];
                v += __shfl_xor(v, 16);
                v += __shfl_xor(v, 32);
                if (quad == 0)
                    atomicAdd(&colpart[task & 1][ncol0 + nt * 16 + l15], v);
            }
        }

        __syncthreads();   // drains prefetch stage + colpart atomics + Bs reads

        // flush col credit (parity buffer: next task uses the other one)
        if (!diag && t < 128) {
            atomicAdd(&rowsum[cbb * 128 + t], colpart[task & 1][t]);
            colpart[task & 1][t] = 0.0f;
        }

        if (!isLast) {
            if (wrap) {                 // switch to row 63-m: flush + reload
                FLUSH_ROWS();
                #pragma unroll
                for (int mt = 0; mt < 4; ++mt)
                    #pragma unroll
                    for (int r = 0; r < 4; ++r) rowpart[mt][r] = 0.0f;
                rb = 63 - m;
                rowbase = rb * 128 + (wid & 1) * 64;
                LOAD_AFRAG();
            }
            cbb = ncbb;
        }
        buf ^= 1;
    }

    FLUSH_ROWS();
    #undef STAGE
    #undef LOAD_AFRAG
    #undef FLUSH_ROWS
}

// ---------------- Kernel C: subtract diag, logs, positive pairs, reduce ----
__global__ __launch_bounds__(256) void finalize_kernel(
    const __bf16* __restrict__ nb, const float* __restrict__ rowsum,
    float* __restrict__ dout)
{
    const int t = threadIdx.x, lane = t & 63, wid = t >> 6;
    const int w = blockIdx.x * 4 + wid;            // 2048 waves, 4 rows each
    float wacc = 0.0f;
    #pragma unroll
    for (int rr = 0; rr < 4; ++rr) {
        const int i = w * 4 + rr;
        const int p = i ^ 4096;                    // partner row (B=4096, pow2)
        // rows i and p share (row&7) so the k-swizzle cancels in the dot
        bf16x2 av = *(const bf16x2*)(nb + (size_t)i * DIM + 2 * lane);
        bf16x2 bv = *(const bf16x2*)(nb + (size_t)p * DIM + 2 * lane);
        float ax = (float)av.x, ay = (float)av.y;
        float bx = (float)bv.x, by = (float)bv.y;
        float self = ax * ax + ay * ay;            // -> 10*log2e exactly as MFMA saw it
        float pos  = ax * bx + ay * by;            // s_pos * log2e
        #pragma unroll
        for (int off = 1; off < 64; off <<= 1) {
            self += __shfl_xor(self, off);
            pos  += __shfl_xor(pos, off);
        }
        if (lane == 0) {
            float se = rowsum[i] - __builtin_amdgcn_exp2f(self);  // drop diagonal
            wacc += logf(se) - pos * LN2;          // lse_nat - s_pos_nat
        }
    }
    if (lane == 0) atomicAdd(dout, wacc * 2048.0f); // * B/2
}

extern "C" void kernel_launch(void* const* d_in, const int* in_sizes, int n_in,
                              void* d_out, int out_size, void* d_ws, size_t ws_size,
                              hipStream_t stream)
{
    const float* out1 = (const float*)d_in[0];
    const float* out2 = (const float*)d_in[1];
    __bf16* nb     = (__bf16*)d_ws;                               // 2 MB
    float*  rowsum = (float*)((char*)d_ws + (size_t)NROWS * DIM * 2); // 32 KB
    float*  dout   = (float*)d_out;

    hipLaunchKernelGGL(norm_kernel, dim3(2048), dim3(256), 0, stream,
                       out1, out2, nb, rowsum, dout);
    hipLaunchKernelGGL(simloss_main, dim3(512), dim3(256), 0, stream,
                       (const __bf16*)nb, rowsum);
    hipLaunchKernelGGL(finalize_kernel, dim3(512), dim3(256), 0, stream,
                       (const __bf16*)nb, rowsum, dout);
}

// Round 3
// 106.481 us; speedup vs baseline: 1.0571x; 1.0337x over previous
//
#include <hip/hip_runtime.h>
#include <hip/hip_bf16.h>
#include <cstdint>

// NT-Xent contrastive loss, B=4096, D=128, T=0.1.
// loss = sum_i [ log(sum_{j!=i} exp(s_ij)) - s_{i,partner(i)} ] * (B/2)
// s_ij = 10 * cos(n_i, n_j).  We store n * sqrt(10*log2e) in bf16 so the
// MFMA accumulator is directly the exp2 argument (s * log2e).
//
// Full-matrix variant (symmetric-credit versions measured +20us: the
// col-credit atomics + widened epilogue cost more than the 0.51x work
// saves, since the compute floor is only ~9us).  This round adds:
//  - pipelined double-buffered B staging (1 barrier/ct, drain hidden
//    under the k-loop; was sync;stage;sync = exposed drain every ct)
//  - 4x wider finalize (2048 waves, 4 rows each)

typedef __bf16 bf16x8 __attribute__((ext_vector_type(8)));
typedef __bf16 bf16x2 __attribute__((ext_vector_type(2)));
typedef float  f32x4  __attribute__((ext_vector_type(4)));

#define NROWS 8192
#define DIM   128
#define ALPHA 3.7982827f            /* sqrt(10 * log2(e)) */
#define LN2   0.6931471805599453f

// ---- async global->LDS, 16B per lane, wave-uniform LDS base ----
__device__ __forceinline__ void load_lds16(const void* g, void* l) {
    __builtin_amdgcn_global_load_lds(
        (const __attribute__((address_space(1))) unsigned int*)(uintptr_t)g,
        (__attribute__((address_space(3))) unsigned int*)(uintptr_t)l,
        16, 0, 0);
}

// K-chunk xor swizzle: element k of row r stored at chunk c' = (c&8)|((c^r)&7),
// c = k>>3.  Keeps ds_read_b128 fragment reads at free 2-way bank conflicts,
// while remaining a contiguous-per-row layout (global_load_lds compatible).

// ---------------- Kernel A: normalize + scale + swizzle + zero ws ----------
__global__ __launch_bounds__(256) void norm_kernel(
    const float* __restrict__ out1, const float* __restrict__ out2,
    __bf16* __restrict__ nb, float* __restrict__ rowsum, float* __restrict__ dout)
{
    const int t = threadIdx.x, lane = t & 63, wid = t >> 6;
    const int row = blockIdx.x * 4 + wid;
    const float* src = (row < 4096) ? (out1 + (size_t)row * DIM)
                                    : (out2 + (size_t)(row - 4096) * DIM);
    float2 v = ((const float2*)src)[lane];
    float ss = v.x * v.x + v.y * v.y;
    #pragma unroll
    for (int off = 1; off < 64; off <<= 1) ss += __shfl_xor(ss, off);
    const float s = rsqrtf(ss) * ALPHA;

    const int c  = lane >> 2;                      // chunk of element 2*lane
    const int cs = (c & 8) | ((c ^ row) & 7);
    const int idx = row * DIM + cs * 8 + ((2 * lane) & 7);
    bf16x2 w;
    w.x = (__bf16)(v.x * s);
    w.y = (__bf16)(v.y * s);
    *(bf16x2*)(nb + idx) = w;

    if (blockIdx.x < 32) rowsum[blockIdx.x * 256 + t] = 0.0f;
    if (blockIdx.x == 0 && t == 0) dout[0] = 0.0f;
}

// ---------------- Kernel B: Gram + exp + per-row sums ----------------------
// grid (64, 8): block = rows [rb*128,+128) x cols [cb*1024,+1024).
// 4 waves in 2x2; each wave owns a 64x64 output tile per 128-col step (ct).
// A-strip fragments register-resident (K=128 fits); B-tiles double-buffered
// via global_load_lds, prefetch issued before the k-loop so the barrier's
// vmcnt(0) drain is hidden under MFMA+exp (T3-minimum pipeline).
__global__ __launch_bounds__(256, 2) void simloss_main(
    const __bf16* __restrict__ nb, float* __restrict__ rowsum)
{
    __shared__ __bf16 Bsm[2][128 * DIM];          // 2 x 32 KB double buffer
    const int t = threadIdx.x, lane = t & 63, wid = t >> 6;
    const int quad = lane >> 4, l15 = lane & 15;
    const int rb = blockIdx.x, cb = blockIdx.y;
    const int rowbase = rb * 128 + (wid & 1) * 64;   // global row of wave tile
    const int ncol0   = (wid >> 1) * 64;             // col offset inside B tile

    // swizzled chunk byte/element offsets per k-step
    int cso[4];
    #pragma unroll
    for (int k = 0; k < 4; ++k) {
        int c = k * 4 + quad;
        cso[k] = ((c & 8) | ((c ^ lane) & 7)) * 8;   // lane&7 == row&7 here
    }

    // stage 128 cols (= 128 contiguous rows of nb = 32 KB) into Bsm[bi]
    #define STAGE(bi, ct_) do {                                              \
        const char* gBw_ = (const char*)(nb + (size_t)(cb * 1024 + (ct_) * 128) * DIM) \
                           + wid * 1024 + lane * 16;                         \
        char* lB_ = (char*)(&Bsm[bi][0]) + wid * 1024;                       \
        _Pragma("unroll")                                                    \
        for (int i_ = 0; i_ < 8; ++i_)                                       \
            load_lds16(gBw_ + i_ * 4096, lB_ + i_ * 4096);                   \
    } while (0)

    // prologue: stage ct=0, load A fragments from global (L2-hot)
    STAGE(0, 0);
    bf16x8 afrag[4][4];
    #pragma unroll
    for (int mt = 0; mt < 4; ++mt) {
        const __bf16* ar = nb + (size_t)(rowbase + mt * 16 + l15) * DIM;
        #pragma unroll
        for (int k = 0; k < 4; ++k) afrag[mt][k] = *(const bf16x8*)(ar + cso[k]);
    }

    float rowpart[4][4] = {};
    __syncthreads();                    // stage0 + afrag drained

    int buf = 0;
    for (int ct = 0; ct < 8; ++ct) {
        if (ct < 7) STAGE(buf ^ 1, ct + 1);   // prefetch next tile, in flight
                                              // across the whole k-loop

        const __bf16* Bs = &Bsm[buf][0];
        f32x4 acc[4][4] = {};
        #pragma unroll
        for (int k = 0; k < 4; ++k) {
            bf16x8 bfr[4];
            #pragma unroll
            for (int nt = 0; nt < 4; ++nt)
                bfr[nt] = *(const bf16x8*)(Bs + (ncol0 + nt * 16 + l15) * DIM + cso[k]);
            #pragma unroll
            for (int mt = 0; mt < 4; ++mt)
                #pragma unroll
                for (int nt = 0; nt < 4; ++nt)
                    acc[mt][nt] = __builtin_amdgcn_mfma_f32_16x16x32_bf16(
                        afrag[mt][k], bfr[nt], acc[mt][nt], 0, 0, 0);
        }

        // epilogue: acc is already s*log2e -> single v_exp_f32 each
        #pragma unroll
        for (int mt = 0; mt < 4; ++mt)
            #pragma unroll
            for (int nt = 0; nt < 4; ++nt)
                #pragma unroll
                for (int r = 0; r < 4; ++r)
                    rowpart[mt][r] += __builtin_amdgcn_exp2f(acc[mt][nt][r]);

        __syncthreads();   // one barrier/ct: drains prefetch (hidden under
                           // the k-loop) and fences Bs reads vs next STAGE
        buf ^= 1;
    }
    #undef STAGE

    // reduce the 16 lanes sharing a quad (cols), one atomic per row
    #pragma unroll
    for (int mt = 0; mt < 4; ++mt)
        #pragma unroll
        for (int r = 0; r < 4; ++r) {
            float v = rowpart[mt][r];
            v += __shfl_xor(v, 1);
            v += __shfl_xor(v, 2);
            v += __shfl_xor(v, 4);
            v += __shfl_xor(v, 8);
            if (l15 == 0)
                atomicAdd(&rowsum[rowbase + mt * 16 + quad * 4 + r], v);
        }
}

// ---------------- Kernel C: subtract diag, logs, positive pairs, reduce ----
__global__ __launch_bounds__(256) void finalize_kernel(
    const __bf16* __restrict__ nb, const float* __restrict__ rowsum,
    float* __restrict__ dout)
{
    const int t = threadIdx.x, lane = t & 63, wid = t >> 6;
    const int w = blockIdx.x * 4 + wid;            // 2048 waves, 4 rows each
    float wacc = 0.0f;
    #pragma unroll
    for (int rr = 0; rr < 4; ++rr) {
        const int i = w * 4 + rr;
        const int p = i ^ 4096;                    // partner row (B=4096, pow2)
        // rows i and p share (row&7) so the k-swizzle cancels in the dot
        bf16x2 av = *(const bf16x2*)(nb + (size_t)i * DIM + 2 * lane);
        bf16x2 bv = *(const bf16x2*)(nb + (size_t)p * DIM + 2 * lane);
        float ax = (float)av.x, ay = (float)av.y;
        float bx = (float)bv.x, by = (float)bv.y;
        float self = ax * ax + ay * ay;            // -> 10*log2e exactly as MFMA saw it
        float pos  = ax * bx + ay * by;            // s_pos * log2e
        #pragma unroll
        for (int off = 1; off < 64; off <<= 1) {
            self += __shfl_xor(self, off);
            pos  += __shfl_xor(pos, off);
        }
        if (lane == 0) {
            float se = rowsum[i] - __builtin_amdgcn_exp2f(self);  // drop diagonal
            wacc += logf(se) - pos * LN2;          // lse_nat - s_pos_nat
        }
    }
    if (lane == 0) atomicAdd(dout, wacc * 2048.0f); // * B/2
}

extern "C" void kernel_launch(void* const* d_in, const int* in_sizes, int n_in,
                              void* d_out, int out_size, void* d_ws, size_t ws_size,
                              hipStream_t stream)
{
    const float* out1 = (const float*)d_in[0];
    const float* out2 = (const float*)d_in[1];
    __bf16* nb     = (__bf16*)d_ws;                               // 2 MB
    float*  rowsum = (float*)((char*)d_ws + (size_t)NROWS * DIM * 2); // 32 KB
    float*  dout   = (float*)d_out;

    hipLaunchKernelGGL(norm_kernel, dim3(2048), dim3(256), 0, stream,
                       out1, out2, nb, rowsum, dout);
    hipLaunchKernelGGL(simloss_main, dim3(64, 8), dim3(256), 0, stream,
                       (const __bf16*)nb, rowsum);
    hipLaunchKernelGGL(finalize_kernel, dim3(512), dim3(256), 0, stream,
                       (const __bf16*)nb, rowsum, dout);
}

// Round 4
// 87.140 us; speedup vs baseline: 1.2917x; 1.2219x over previous
//
#include <hip/hip_runtime.h>
#include <hip/hip_bf16.h>
#include <cstdint>

// NT-Xent contrastive loss, B=4096, D=128, T=0.1.
// loss = sum_i [ log(sum_{j!=i} exp(s_ij)) - s_{i,partner(i)} ] * (B/2)
// s_ij = 10 * cos(n_i, n_j).  We store n * sqrt(10*log2e) in bf16 so the
// MFMA accumulator is directly the exp2 argument (s * log2e).
//
// Budget model (rounds 0-3): dur_us = ~83us harness poison fill (2x 256MiB
// memsets at ~6.4TB/s) + ~9us kernels.  Rounds 1-3 regressions tracked
// same-address global-atomic serialization (~30cyc each at the coherence
// point), NOT compute.  So: simloss/norm stay at the proven round-0 form;
// finalize is widened 4x (2048 waves, latency hiding for the shfl chains)
// but keeps global atomics at 512 (one per block, via LDS block-reduce).

typedef __bf16 bf16x8 __attribute__((ext_vector_type(8)));
typedef __bf16 bf16x2 __attribute__((ext_vector_type(2)));
typedef float  f32x4  __attribute__((ext_vector_type(4)));

#define NROWS 8192
#define DIM   128
#define ALPHA 3.7982827f            /* sqrt(10 * log2(e)) */
#define LN2   0.6931471805599453f

// ---- async global->LDS, 16B per lane, wave-uniform LDS base ----
__device__ __forceinline__ void load_lds16(const void* g, void* l) {
    __builtin_amdgcn_global_load_lds(
        (const __attribute__((address_space(1))) unsigned int*)(uintptr_t)g,
        (__attribute__((address_space(3))) unsigned int*)(uintptr_t)l,
        16, 0, 0);
}

// K-chunk xor swizzle: element k of row r stored at chunk c' = (c&8)|((c^r)&7),
// c = k>>3.  Keeps ds_read_b128 fragment reads at free 2-way bank conflicts,
// while remaining a contiguous-per-row layout (global_load_lds compatible).

// ---------------- Kernel A: normalize + scale + swizzle + zero ws ----------
__global__ __launch_bounds__(256) void norm_kernel(
    const float* __restrict__ out1, const float* __restrict__ out2,
    __bf16* __restrict__ nb, float* __restrict__ rowsum, float* __restrict__ dout)
{
    const int t = threadIdx.x, lane = t & 63, wid = t >> 6;
    const int row = blockIdx.x * 4 + wid;
    const float* src = (row < 4096) ? (out1 + (size_t)row * DIM)
                                    : (out2 + (size_t)(row - 4096) * DIM);
    float2 v = ((const float2*)src)[lane];
    float ss = v.x * v.x + v.y * v.y;
    #pragma unroll
    for (int off = 1; off < 64; off <<= 1) ss += __shfl_xor(ss, off);
    const float s = rsqrtf(ss) * ALPHA;

    const int c  = lane >> 2;                      // chunk of element 2*lane
    const int cs = (c & 8) | ((c ^ row) & 7);
    const int idx = row * DIM + cs * 8 + ((2 * lane) & 7);
    bf16x2 w;
    w.x = (__bf16)(v.x * s);
    w.y = (__bf16)(v.y * s);
    *(bf16x2*)(nb + idx) = w;

    if (blockIdx.x < 32) rowsum[blockIdx.x * 256 + t] = 0.0f;
    if (blockIdx.x == 0 && t == 0) dout[0] = 0.0f;
}

// ---------------- Kernel B: Gram + exp + per-row sums ----------------------
// grid (64, 8): block = rows [rb*128,+128) x cols [cb*1024,+1024).
// 4 waves in 2x2; each wave owns a 64x64 output tile per 128-col iteration.
// A-strip fragments register-resident (K=128 fits); B-tiles via global_load_lds.
// (Proven round-0 form; 1-barrier dbuf variant measured neutral-to-worse.)
__global__ __launch_bounds__(256, 2) void simloss_main(
    const __bf16* __restrict__ nb, float* __restrict__ rowsum)
{
    __shared__ __bf16 Bsm[128 * DIM];             // 32 KB
    const int t = threadIdx.x, lane = t & 63, wid = t >> 6;
    const int quad = lane >> 4, l15 = lane & 15;
    const int rb = blockIdx.x, cb = blockIdx.y;
    const int rowbase = rb * 128 + (wid & 1) * 64;   // global row of wave tile
    const int ncol0   = (wid >> 1) * 64;             // col offset inside B tile

    // swizzled chunk byte/element offsets per k-step
    int cso[4];
    #pragma unroll
    for (int k = 0; k < 4; ++k) {
        int c = k * 4 + quad;
        cso[k] = ((c & 8) | ((c ^ lane) & 7)) * 8;   // lane&7 == row&7 here
    }

    // A fragments from global (L2-hot), 16 x 16B per lane
    bf16x8 afrag[4][4];
    #pragma unroll
    for (int mt = 0; mt < 4; ++mt) {
        const __bf16* ar = nb + (size_t)(rowbase + mt * 16 + l15) * DIM;
        #pragma unroll
        for (int k = 0; k < 4; ++k) afrag[mt][k] = *(const bf16x8*)(ar + cso[k]);
    }

    float rowpart[4][4] = {};

    for (int ct = 0; ct < 8; ++ct) {
        __syncthreads();
        // stage 128 cols (= 128 contiguous rows of nb) into LDS: 32 KB
        const char* gB = (const char*)(nb + (size_t)(cb * 1024 + ct * 128) * DIM);
        char* lB = (char*)Bsm + wid * 1024;
        const char* gBw = gB + wid * 1024 + lane * 16;
        #pragma unroll
        for (int i = 0; i < 8; ++i) load_lds16(gBw + i * 4096, lB + i * 4096);
        __syncthreads();

        f32x4 acc[4][4] = {};
        #pragma unroll
        for (int k = 0; k < 4; ++k) {
            bf16x8 b[4];
            #pragma unroll
            for (int nt = 0; nt < 4; ++nt)
                b[nt] = *(const bf16x8*)(Bsm + (ncol0 + nt * 16 + l15) * DIM + cso[k]);
            #pragma unroll
            for (int mt = 0; mt < 4; ++mt)
                #pragma unroll
                for (int nt = 0; nt < 4; ++nt)
                    acc[mt][nt] = __builtin_amdgcn_mfma_f32_16x16x32_bf16(
                        afrag[mt][k], b[nt], acc[mt][nt], 0, 0, 0);
        }

        // epilogue: acc is already s*log2e -> single v_exp_f32 each
        #pragma unroll
        for (int mt = 0; mt < 4; ++mt)
            #pragma unroll
            for (int nt = 0; nt < 4; ++nt)
                #pragma unroll
                for (int r = 0; r < 4; ++r)
                    rowpart[mt][r] += __builtin_amdgcn_exp2f(acc[mt][nt][r]);
    }

    // reduce the 16 lanes sharing a quad (cols), one atomic per row
    #pragma unroll
    for (int mt = 0; mt < 4; ++mt)
        #pragma unroll
        for (int r = 0; r < 4; ++r) {
            float v = rowpart[mt][r];
            v += __shfl_xor(v, 1);
            v += __shfl_xor(v, 2);
            v += __shfl_xor(v, 4);
            v += __shfl_xor(v, 8);
            if (l15 == 0)
                atomicAdd(&rowsum[rowbase + mt * 16 + quad * 4 + r], v);
        }
}

// ---------------- Kernel C: subtract diag, logs, positive pairs, reduce ----
// 512 blocks x 4 waves x 4 rows = 8192 rows.  Per-block LDS reduction keeps
// same-address global atomics at 512 (one per block) -- the round-3 version
// with 2048 per-wave atomics to dout regressed ~+14us (serialized RMW tail).
__global__ __launch_bounds__(256) void finalize_kernel(
    const __bf16* __restrict__ nb, const float* __restrict__ rowsum,
    float* __restrict__ dout)
{
    __shared__ float sred[4];
    const int t = threadIdx.x, lane = t & 63, wid = t >> 6;
    const int w = blockIdx.x * 4 + wid;            // 2048 waves, 4 rows each
    float wacc = 0.0f;
    #pragma unroll
    for (int rr = 0; rr < 4; ++rr) {
        const int i = w * 4 + rr;
        const int p = i ^ 4096;                    // partner row (B=4096, pow2)
        // rows i and p share (row&7) so the k-swizzle cancels in the dot
        bf16x2 av = *(const bf16x2*)(nb + (size_t)i * DIM + 2 * lane);
        bf16x2 bv = *(const bf16x2*)(nb + (size_t)p * DIM + 2 * lane);
        float ax = (float)av.x, ay = (float)av.y;
        float bx = (float)bv.x, by = (float)bv.y;
        float self = ax * ax + ay * ay;            // -> 10*log2e exactly as MFMA saw it
        float pos  = ax * bx + ay * by;            // s_pos * log2e
        #pragma unroll
        for (int off = 1; off < 64; off <<= 1) {
            self += __shfl_xor(self, off);
            pos  += __shfl_xor(pos, off);
        }
        if (lane == 0) {
            float se = rowsum[i] - __builtin_amdgcn_exp2f(self);  // drop diagonal
            wacc += logf(se) - pos * LN2;          // lse_nat - s_pos_nat
        }
    }
    if (lane == 0) sred[wid] = wacc;
    __syncthreads();
    if (t == 0) {
        float bl = (sred[0] + sred[1]) + (sred[2] + sred[3]);
        atomicAdd(dout, bl * 2048.0f);             // * B/2, one atomic per block
    }
}

extern "C" void kernel_launch(void* const* d_in, const int* in_sizes, int n_in,
                              void* d_out, int out_size, void* d_ws, size_t ws_size,
                              hipStream_t stream)
{
    const float* out1 = (const float*)d_in[0];
    const float* out2 = (const float*)d_in[1];
    __bf16* nb     = (__bf16*)d_ws;                               // 2 MB
    float*  rowsum = (float*)((char*)d_ws + (size_t)NROWS * DIM * 2); // 32 KB
    float*  dout   = (float*)d_out;

    hipLaunchKernelGGL(norm_kernel, dim3(2048), dim3(256), 0, stream,
                       out1, out2, nb, rowsum, dout);
    hipLaunchKernelGGL(simloss_main, dim3(64, 8), dim3(256), 0, stream,
                       (const __bf16*)nb, rowsum);
    hipLaunchKernelGGL(finalize_kernel, dim3(512), dim3(256), 0, stream,
                       (const __bf16*)nb, rowsum, dout);
}